// Round 4
// baseline (70.900 us; speedup 1.0000x reference)
//
#include <hip/hip_runtime.h>

#define NB1   123
#define NCSd  96
#define SW    538
#define EPB   16      // elements per block (k_fast)
#define TPB   256
#define BT    16      // elements per block (k_solve)
#define STPB  128
#define LROW  540     // padded LDS row stride (floats); 540%32=28 spreads banks

// ---------------- ws layout ----------------
// [0] float    R   = max_j ||K_j||_2 (complex row norm)
// [1] float    dW  = max_j |W_j - 1|
// [2] unsigned count of flagged elements
// [3 .. 3+B)   unsigned flagged element indices
// required: (3 + 32768) * 4 bytes

// ---- R/dW in one small parallel kernel: wave w reduces rows w, w+4, ... ----
__global__ __launch_bounds__(256) void k_norm(const float* __restrict__ Kre,
                                              const float* __restrict__ Kim,
                                              const float* __restrict__ Lre,
                                              const float* __restrict__ Lim,
                                              float* __restrict__ ws) {
    __shared__ float wred[8];
    const int tid = threadIdx.x;
    const int w = tid >> 6, l = tid & 63;
    float rmax2 = 0.f;
    for (int j = w; j < NB1; j += 4) {
        const float* kr = Kre + j * NB1;
        const float* ki = Kim + j * NB1;
        float a = kr[l], bb = ki[l];                 // l < 64 < 123: always valid
        float s = fmaf(a, a, bb * bb);
        if (l + 64 < NB1) {
            float a2 = kr[l + 64], b2 = ki[l + 64];
            s = fmaf(a2, a2, fmaf(b2, b2, s));
        }
        #pragma unroll
        for (int off = 32; off; off >>= 1) s += __shfl_xor(s, off);
        rmax2 = fmaxf(rmax2, s);                     // row-norm^2, same on all lanes
    }
    float dw2 = 0.f;
    if (w == 0) {
        float dr = Lre[l] - 1.f, di = Lim[l];
        dw2 = fmaf(dr, dr, di * di);
        if (l + 64 < NB1) {
            float dr2 = Lre[l + 64] - 1.f, di2 = Lim[l + 64];
            dw2 = fmaxf(dw2, fmaf(dr2, dr2, di2 * di2));
        }
        #pragma unroll
        for (int off = 32; off; off >>= 1) dw2 = fmaxf(dw2, __shfl_xor(dw2, off));
    }
    if (l == 0) { wred[w] = rmax2; wred[4 + w] = dw2; }
    __syncthreads();
    if (tid == 0) {
        float r2 = fmaxf(fmaxf(wred[0], wred[1]), fmaxf(wred[2], wred[3]));
        ws[0] = sqrtf(r2);
        ws[1] = sqrtf(wred[4]);
        ((unsigned*)ws)[2] = 0u;
    }
}

// ---- main: LDS-staged rows (coalesced f2), costs + user_sat + certificate ----
__global__ __launch_bounds__(TPB) void k_fast(const float* __restrict__ action,
                                              const float* __restrict__ state,
                                              float* __restrict__ ws,
                                              float* __restrict__ out) {
    __shared__ float st[EPB][LROW];
    __shared__ float ev[EPB][128];
    const int tid = threadIdx.x;
    const long e0 = (long)blockIdx.x * EPB;

    // Stage 16 rows: 269 float2 per row, consecutive lanes -> consecutive 8B
    for (int idx = tid; idx < EPB * 269; idx += TPB) {
        int e = idx / 269, c = idx - e * 269;
        float2 v = *(const float2*)(state + (e0 + e) * SW + 2 * c);
        *(float2*)&st[e][2 * c] = v;                 // (540e+2c)*4 is 8B-aligned
    }
    for (int x = tid; x < EPB * 128; x += TPB) ((float*)ev)[x] = 0.f;
    __syncthreads();

    const int e = tid >> 4, l = tid & 15;
    const long b = e0 + e;
    const float* srow = st[e];
    const float pr = srow[3];
    float costL = 0.f, usatL = 0.f;
    #pragma unroll
    for (int s = 0; s < NCSd / 16; ++s) {
        int i = l + 16 * s;
        float cap = srow[250 + 3 * i];
        float tl  = srow[251 + 3 * i];
        int   bus = (int)srow[252 + 3 * i];
        float a   = action[b * NCSd + i];            // coalesced across lanes
        float conn = cap > 0.f ? 1.f : 0.f;
        float mch = fminf(22.0f,  conn * (70.0f - cap) * 4.0f);   // /DT, DT=0.25 exact
        float mds = fmaxf(-22.0f, conn * (15.0f - cap) * 4.0f);
        float p = fmaxf(fminf(22.17f * a, mch), mds);             // MAX_CS = -MIN_CS
        costL = fmaf(pr * p, 0.25f, costL);
        float nc = ceilf((cap + p * 0.25f) * 100.0f) * 0.01f;
        if (tl == 1.0f) { float d = nc - 70.0f; usatL = fmaf(-10.0f * d, d, usatL); }
        atomicAdd(&ev[e][bus], p);
    }
    __syncthreads();

    // q^2 = sum_k (ap+ev)^2 + rp^2
    float s2 = 0.f;
    for (int k = l; k < NB1; k += 16) {
        float apv = srow[4 + k] + ev[e][k];
        float rpv = srow[127 + k];
        s2 = fmaf(apv, apv, fmaf(rpv, rpv, s2));
    }
    #pragma unroll
    for (int off = 8; off; off >>= 1) {
        s2    += __shfl_xor(s2, off);
        costL += __shfl_xor(costL, off);
        usatL += __shfl_xor(usatL, off);
    }

    bool flagged = false;
    if (l == 0) {
        float q  = sqrtf(s2) * 0.001f;               // ||S||_2
        float R  = ws[0];
        float dW = ws[1];
        float x  = R * q * 1.001f + 1e-7f;           // fp-safety inflation
        float om = 1.0f - dW;
        float disc = om * om - 4.0f * x;
        bool safe = false;
        if (disc > 0.f) {
            float m = 0.5f * (om + sqrtf(disc));      // lower bound on |v_j| over all iterates
            safe = (dW + x / m) < 0.0495f;            // => every |1-|v|| < 0.05 => term == 0
        }
        flagged = !safe;
        out[b] = costL + usatL;
    }
    unsigned long long mask = __ballot(flagged);
    if (mask) {
        int nf = __popcll(mask);
        int lead = __ffsll((long long)mask) - 1;
        int lane = tid & 63;
        unsigned base_ = 0;
        if (lane == lead) base_ = atomicAdd(((unsigned*)ws) + 2, (unsigned)nf);
        base_ = __shfl(base_, lead);
        if (flagged) {
            int rank = __popcll(mask & ((1ull << lane) - 1ull));
            ((unsigned*)ws)[3 + base_ + rank] = (unsigned)b;
        }
    }
}

// ---- batched exact solve for flagged elements (expected: none) ----
__global__ __launch_bounds__(STPB) void k_solve(const float* __restrict__ action,
                                                const float* __restrict__ state,
                                                const float* __restrict__ Kre,
                                                const float* __restrict__ Kim,
                                                const float* __restrict__ Lre,
                                                const float* __restrict__ Lim,
                                                const float* __restrict__ ws,
                                                float* __restrict__ out) {
    __shared__ float ev[BT][STPB];
    __shared__ __align__(16) float2 cmat[STPB][BT + 2];
    __shared__ float vls[STPB][BT + 1];
    __shared__ float red[2];
    __shared__ unsigned idxs[BT];
    const unsigned count = ((const unsigned*)ws)[2];
    const int tid = threadIdx.x;
    const int j = tid;
    const bool jok = j < NB1;
    const float Wre = jok ? Lre[j] : 1.f;
    const float Wim = jok ? Lim[j] : 0.f;

    for (unsigned base = (unsigned)blockIdx.x * BT; base < count; base += (unsigned)gridDim.x * BT) {
        unsigned nv = count - base; if (nv > BT) nv = BT;
        if (tid < BT) {
            unsigned t = (unsigned)tid < nv ? (unsigned)tid : nv - 1;
            idxs[tid] = ((const unsigned*)ws)[3 + base + t];
        }
        for (int x = tid; x < BT * STPB; x += STPB) ((float*)ev)[x] = 0.f;
        __syncthreads();

        for (int task = tid; task < BT * NCSd; task += STPB) {
            int e = task / NCSd, i = task - e * NCSd;
            long b = (long)idxs[e];
            const float* srow = state + b * SW;
            float cap = srow[250 + 3 * i];
            int   bus = (int)srow[252 + 3 * i];
            float a   = action[b * NCSd + i];
            float conn = cap > 0.f ? 1.f : 0.f;
            float mch = fminf(22.0f,  conn * (70.0f - cap) * 4.0f);
            float mds = fmaxf(-22.0f, conn * (15.0f - cap) * 4.0f);
            float p = fmaxf(fminf(22.17f * a, mch), mds);
            atomicAdd(&ev[e][bus], p);
        }
        __syncthreads();

        float Sre[BT], Sim[BT], vr[BT], vi[BT];
        #pragma unroll
        for (int e = 0; e < BT; ++e) {
            long b = (long)idxs[e];
            float ap = jok ? state[b * SW + 4 + j]   : 0.f;
            float rp = jok ? state[b * SW + 127 + j] : 0.f;
            Sre[e] = (ap + ev[e][j]) * 0.001f;
            Sim[e] = rp * 0.001f;
            vr[e] = 1.f; vi[e] = 0.f;
        }
        for (int it = 0; it < 100; ++it) {
            #pragma unroll
            for (int e = 0; e < BT; ++e) {
                float d = vr[e] * vr[e] + vi[e] * vi[e];
                float inv = 1.0f / d;
                cmat[j][e] = make_float2((Sre[e] * vr[e] + Sim[e] * vi[e]) * inv,
                                         (Sre[e] * vi[e] - Sim[e] * vr[e]) * inv);
            }
            __syncthreads();
            float ar[BT], ai[BT];
            #pragma unroll
            for (int e = 0; e < BT; ++e) { ar[e] = Wre; ai[e] = Wim; }
            for (int k = 0; k < NB1; ++k) {
                float kr = jok ? Kre[j * NB1 + k] : 0.f;
                float ki = jok ? Kim[j * NB1 + k] : 0.f;
                const float4* crow = (const float4*)(&cmat[k][0]);
                #pragma unroll
                for (int eh = 0; eh < BT / 2; ++eh) {
                    float4 c2 = crow[eh];
                    ar[2*eh]   = fmaf(kr, c2.x, fmaf(-ki, c2.y, ar[2*eh]));
                    ai[2*eh]   = fmaf(kr, c2.y, fmaf( ki, c2.x, ai[2*eh]));
                    ar[2*eh+1] = fmaf(kr, c2.z, fmaf(-ki, c2.w, ar[2*eh+1]));
                    ai[2*eh+1] = fmaf(kr, c2.w, fmaf( ki, c2.z, ai[2*eh+1]));
                }
            }
            float md = 0.f;
            #pragma unroll
            for (int e = 0; e < BT; ++e) {
                float vmn = sqrtf(ar[e]*ar[e] + ai[e]*ai[e]);
                float vmo = sqrtf(vr[e]*vr[e] + vi[e]*vi[e]);
                md = fmaxf(md, fabsf(vmn - vmo));
                vr[e] = ar[e]; vi[e] = ai[e];
            }
            #pragma unroll
            for (int off = 32; off; off >>= 1) md = fmaxf(md, __shfl_xor(md, off));
            if ((tid & 63) == 0) red[tid >> 6] = md;
            __syncthreads();
            if (fmaxf(red[0], red[1]) < 1e-6f) break;
        }
        #pragma unroll
        for (int e = 0; e < BT; ++e) {
            float vm = sqrtf(vr[e]*vr[e] + vi[e]*vi[e]);
            vls[j][e] = jok ? fminf(0.f, 0.05f - fabsf(1.0f - vm)) : 0.f;
        }
        __syncthreads();
        if (tid < (int)nv) {
            float s = 0.f;
            for (int k = 0; k < NB1; ++k) s += vls[k][tid];
            long b = (long)idxs[tid];
            out[b] += 1000.0f * s;
        }
        __syncthreads();
    }
}

// ================= legacy full-solve path (used only if ws too small) =================
__global__ __launch_bounds__(STPB) void k_main(
    const float* __restrict__ action, const float* __restrict__ state,
    const float* __restrict__ Kre, const float* __restrict__ Kim,
    const float* __restrict__ Lre, const float* __restrict__ Lim,
    float* __restrict__ out)
{
    __shared__ float ev[BT][STPB];
    __shared__ float costs_s[BT];
    __shared__ float usat_s[BT];
    __shared__ __align__(16) float2 cmat[STPB][BT + 2];
    __shared__ float vls[STPB][BT + 1];
    __shared__ float red[2];
    const int tid = threadIdx.x;
    const int e0  = blockIdx.x * BT;
    for (int x = tid; x < BT * STPB; x += STPB) ((float*)ev)[x] = 0.f;
    if (tid < BT) { costs_s[tid] = 0.f; usat_s[tid] = 0.f; }
    __syncthreads();
    for (int task = tid; task < BT * NCSd; task += STPB) {
        int e = task / NCSd, i = task - e * NCSd;
        long b = (long)(e0 + e);
        const float* srow = state + b * SW;
        float cap = srow[250 + 3 * i], tleft = srow[251 + 3 * i];
        int bus = (int)srow[252 + 3 * i];
        float a = action[b * NCSd + i];
        float conn = cap > 0.f ? 1.f : 0.f;
        float mch = fminf(22.0f, conn * (70.0f - cap) * 4.0f);
        float mds = fmaxf(-22.0f, conn * (15.0f - cap) * 4.0f);
        float power = fmaxf(fminf(22.17f * a, mch), mds);
        atomicAdd(&costs_s[e], srow[3] * power * 0.25f);
        float nc = ceilf((cap + power * 0.25f) * 100.0f) * 0.01f;
        if (tleft == 1.0f) { float d = nc - 70.0f; atomicAdd(&usat_s[e], -10.0f * d * d); }
        atomicAdd(&ev[e][bus], power);
    }
    __syncthreads();
    const int j = tid;
    const bool jok = j < NB1;
    float Wre = jok ? Lre[j] : 1.0f, Wim = jok ? Lim[j] : 0.0f;
    float Sre[BT], Sim[BT], vr[BT], vi[BT];
    #pragma unroll
    for (int e = 0; e < BT; ++e) {
        long b = (long)(e0 + e);
        float ap = jok ? state[b * SW + 4 + j] : 0.f;
        float rp = jok ? state[b * SW + 127 + j] : 0.f;
        Sre[e] = (ap + ev[e][j]) * 0.001f; Sim[e] = rp * 0.001f;
        vr[e] = 1.f; vi[e] = 0.f;
    }
    for (int it = 0; it < 100; ++it) {
        #pragma unroll
        for (int e = 0; e < BT; ++e) {
            float d = vr[e]*vr[e] + vi[e]*vi[e];
            float inv = 1.0f / d;
            cmat[j][e] = make_float2((Sre[e]*vr[e] + Sim[e]*vi[e]) * inv,
                                     (Sre[e]*vi[e] - Sim[e]*vr[e]) * inv);
        }
        __syncthreads();
        float ar[BT], ai[BT];
        #pragma unroll
        for (int e = 0; e < BT; ++e) { ar[e] = Wre; ai[e] = Wim; }
        for (int k = 0; k < NB1; ++k) {
            float kr = jok ? Kre[j*NB1+k] : 0.f;
            float ki = jok ? Kim[j*NB1+k] : 0.f;
            const float4* crow = (const float4*)(&cmat[k][0]);
            #pragma unroll
            for (int eh = 0; eh < BT / 2; ++eh) {
                float4 c2 = crow[eh];
                ar[2*eh]   = fmaf(kr, c2.x, fmaf(-ki, c2.y, ar[2*eh]));
                ai[2*eh]   = fmaf(kr, c2.y, fmaf( ki, c2.x, ai[2*eh]));
                ar[2*eh+1] = fmaf(kr, c2.z, fmaf(-ki, c2.w, ar[2*eh+1]));
                ai[2*eh+1] = fmaf(kr, c2.w, fmaf( ki, c2.z, ai[2*eh+1]));
            }
        }
        float md = 0.f;
        #pragma unroll
        for (int e = 0; e < BT; ++e) {
            float vmn = sqrtf(ar[e]*ar[e] + ai[e]*ai[e]);
            float vmo = sqrtf(vr[e]*vr[e] + vi[e]*vi[e]);
            md = fmaxf(md, fabsf(vmn - vmo));
            vr[e] = ar[e]; vi[e] = ai[e];
        }
        #pragma unroll
        for (int off = 32; off > 0; off >>= 1) md = fmaxf(md, __shfl_xor(md, off));
        if ((tid & 63) == 0) red[tid >> 6] = md;
        __syncthreads();
        if (fmaxf(red[0], red[1]) < 1e-6f) break;
    }
    #pragma unroll
    for (int e = 0; e < BT; ++e) {
        float vm = sqrtf(vr[e]*vr[e] + vi[e]*vi[e]);
        vls[j][e] = jok ? fminf(0.f, 0.05f - fabsf(1.0f - vm)) : 0.f;
    }
    __syncthreads();
    if (tid < BT) {
        float s = 0.f;
        for (int k = 0; k < NB1; ++k) s += vls[k][tid];
        out[e0 + tid] = 1000.0f * s + costs_s[tid] + usat_s[tid];
    }
}

extern "C" void kernel_launch(void* const* d_in, const int* in_sizes, int n_in,
                              void* d_out, int out_size, void* d_ws, size_t ws_size,
                              hipStream_t stream) {
    const float* action = (const float*)d_in[0];
    const float* state  = (const float*)d_in[1];
    const float* Kre    = (const float*)d_in[2];
    const float* Kim    = (const float*)d_in[3];
    const float* Lre    = (const float*)d_in[4];
    const float* Lim    = (const float*)d_in[5];
    float* out = (float*)d_out;
    const int B = out_size;                        // 32768

    const size_t wsNeed = (size_t)(3 + B) * sizeof(unsigned);
    if (ws_size >= wsNeed) {
        float* ws = (float*)d_ws;
        hipLaunchKernelGGL(k_norm, dim3(1), dim3(256), 0, stream, Kre, Kim, Lre, Lim, ws);
        hipLaunchKernelGGL(k_fast, dim3(B / EPB), dim3(TPB), 0, stream,
                           action, state, ws, out);
        hipLaunchKernelGGL(k_solve, dim3(256), dim3(STPB), 0, stream,
                           action, state, Kre, Kim, Lre, Lim, ws, out);
    } else {
        hipLaunchKernelGGL(k_main, dim3((B + BT - 1) / BT), dim3(STPB), 0, stream,
                           action, state, Kre, Kim, Lre, Lim, out);
    }
}

// Round 5
// 50.648 us; speedup vs baseline: 1.3999x; 1.3999x over previous
//
#include <hip/hip_runtime.h>

#define NB1   123
#define NCSd  96
#define SW    538
#define EPB   8       // elements per block (k_fast); LDS 21.3 KB -> 7 blocks/CU
#define TPB   256
#define BT    16      // elements per block (k_solve)
#define STPB  128

// ---------------- ws layout ----------------
// [0] float    R   = max_j ||K_j||_2 (complex row norm)
// [1] float    dW  = max_j |W_j - 1|
// [2] unsigned count of flagged elements
// [3 .. 3+B)   unsigned flagged element indices

// ---- R/dW: one block, 8 waves, wave w reduces rows w, w+8, ... ----
__global__ __launch_bounds__(512) void k_norm(const float* __restrict__ Kre,
                                              const float* __restrict__ Kim,
                                              const float* __restrict__ Lre,
                                              const float* __restrict__ Lim,
                                              float* __restrict__ ws) {
    __shared__ float wred[16];
    const int tid = threadIdx.x;
    const int w = tid >> 6, l = tid & 63;
    float rmax2 = 0.f;
    for (int j = w; j < NB1; j += 8) {
        const float* kr = Kre + j * NB1;
        const float* ki = Kim + j * NB1;
        float a = kr[l], bb = ki[l];                 // l < 64 <= 123: valid
        float s = fmaf(a, a, bb * bb);
        if (l + 64 < NB1) {
            float a2 = kr[l + 64], b2 = ki[l + 64];
            s = fmaf(a2, a2, fmaf(b2, b2, s));
        }
        #pragma unroll
        for (int off = 32; off; off >>= 1) s += __shfl_xor(s, off);
        rmax2 = fmaxf(rmax2, s);
    }
    float dw2 = 0.f;
    if (w == 0) {
        float dr = Lre[l] - 1.f, di = Lim[l];
        dw2 = fmaf(dr, dr, di * di);
        if (l + 64 < NB1) {
            float dr2 = Lre[l + 64] - 1.f, di2 = Lim[l + 64];
            dw2 = fmaxf(dw2, fmaf(dr2, dr2, di2 * di2));
        }
        #pragma unroll
        for (int off = 32; off; off >>= 1) dw2 = fmaxf(dw2, __shfl_xor(dw2, off));
    }
    if (l == 0) { wred[w] = rmax2; wred[8 + w] = dw2; }
    __syncthreads();
    if (tid == 0) {
        float r2 = wred[0];
        #pragma unroll
        for (int i = 1; i < 8; ++i) r2 = fmaxf(r2, wred[i]);
        ws[0] = sqrtf(r2);
        ws[1] = sqrtf(wred[8]);
        ((unsigned*)ws)[2] = 0u;
    }
}

// ---- main: linear LDS row copy (8 rows), 32 lanes/element, certificate ----
__global__ __launch_bounds__(TPB) void k_fast(const float* __restrict__ action,
                                              const float* __restrict__ state,
                                              float* __restrict__ ws,
                                              float* __restrict__ out) {
    __shared__ __align__(16) float st[EPB * SW];     // exact contiguous copy of 8 rows
    __shared__ float ev[EPB][128];
    const int tid = threadIdx.x;
    const long e0 = (long)blockIdx.x * EPB;

    // Stage: 8*269 = 2152 float2, fully linear global->LDS
    {
        const float* gbase = state + e0 * SW;
        for (int idx = tid; idx < EPB * (SW / 2); idx += TPB)
            *(float2*)&st[2 * idx] = *(const float2*)(gbase + 2 * idx);
    }
    for (int x = tid; x < EPB * 128; x += TPB) ((float*)ev)[x] = 0.f;
    __syncthreads();

    const int e = tid >> 5, l = tid & 31;            // 32 lanes per element
    const long b = e0 + e;
    const float* srow = st + e * SW;
    const float pr = srow[3];                        // broadcast
    float costL = 0.f, usatL = 0.f;
    #pragma unroll
    for (int s = 0; s < NCSd / 32; ++s) {
        int i = l + 32 * s;
        float cap = srow[250 + 3 * i];
        float tl  = srow[251 + 3 * i];
        int   bus = (int)srow[252 + 3 * i];
        float a   = action[b * NCSd + i];            // dense 128B per element
        float conn = cap > 0.f ? 1.f : 0.f;
        float mch = fminf(22.0f,  conn * (70.0f - cap) * 4.0f);   // /DT, DT=0.25 exact
        float mds = fmaxf(-22.0f, conn * (15.0f - cap) * 4.0f);
        float p = fmaxf(fminf(22.17f * a, mch), mds);             // MAX_CS = -MIN_CS
        costL = fmaf(pr * p, 0.25f, costL);
        float nc = ceilf((cap + p * 0.25f) * 100.0f) * 0.01f;
        if (tl == 1.0f) { float d = nc - 70.0f; usatL = fmaf(-10.0f * d, d, usatL); }
        atomicAdd(&ev[e][bus], p);
    }
    __syncthreads();

    // q^2 = sum_k (ap+ev)^2 + rp^2
    float s2 = 0.f;
    #pragma unroll
    for (int s = 0; s < 4; ++s) {
        int k = l + 32 * s;
        if (k < NB1) {
            float apv = srow[4 + k] + ev[e][k];
            float rpv = srow[127 + k];
            s2 = fmaf(apv, apv, fmaf(rpv, rpv, s2));
        }
    }
    #pragma unroll
    for (int off = 16; off; off >>= 1) {
        s2    += __shfl_xor(s2, off);
        costL += __shfl_xor(costL, off);
        usatL += __shfl_xor(usatL, off);
    }

    bool flagged = false;
    if (l == 0) {
        float q  = sqrtf(s2) * 0.001f;               // ||S||_2
        float R  = ws[0];
        float dW = ws[1];
        float x  = R * q * 1.001f + 1e-7f;           // fp-safety inflation
        float om = 1.0f - dW;
        float disc = om * om - 4.0f * x;
        bool safe = false;
        if (disc > 0.f) {
            float m = 0.5f * (om + sqrtf(disc));      // lower bound on |v_j| over all iterates
            safe = (dW + x / m) < 0.0495f;            // => every |1-|v|| < 0.05 => term == 0
        }
        flagged = !safe;
        out[b] = costL + usatL;
    }
    unsigned long long mask = __ballot(flagged);
    if (mask) {
        int nf = __popcll(mask);
        int lead = __ffsll((long long)mask) - 1;
        int lane = tid & 63;
        unsigned base_ = 0;
        if (lane == lead) base_ = atomicAdd(((unsigned*)ws) + 2, (unsigned)nf);
        base_ = __shfl(base_, lead);
        if (flagged) {
            int rank = __popcll(mask & ((1ull << lane) - 1ull));
            ((unsigned*)ws)[3 + base_ + rank] = (unsigned)b;
        }
    }
}

// ---- batched exact solve for flagged elements (expected: none) ----
__global__ __launch_bounds__(STPB) void k_solve(const float* __restrict__ action,
                                                const float* __restrict__ state,
                                                const float* __restrict__ Kre,
                                                const float* __restrict__ Kim,
                                                const float* __restrict__ Lre,
                                                const float* __restrict__ Lim,
                                                const float* __restrict__ ws,
                                                float* __restrict__ out) {
    __shared__ float ev[BT][STPB];
    __shared__ __align__(16) float2 cmat[STPB][BT + 2];
    __shared__ float vls[STPB][BT + 1];
    __shared__ float red[2];
    __shared__ unsigned idxs[BT];
    const unsigned count = ((const unsigned*)ws)[2];
    const int tid = threadIdx.x;
    const int j = tid;
    const bool jok = j < NB1;
    const float Wre = jok ? Lre[j] : 1.f;
    const float Wim = jok ? Lim[j] : 0.f;

    for (unsigned base = (unsigned)blockIdx.x * BT; base < count; base += (unsigned)gridDim.x * BT) {
        unsigned nv = count - base; if (nv > BT) nv = BT;
        if (tid < BT) {
            unsigned t = (unsigned)tid < nv ? (unsigned)tid : nv - 1;
            idxs[tid] = ((const unsigned*)ws)[3 + base + t];
        }
        for (int x = tid; x < BT * STPB; x += STPB) ((float*)ev)[x] = 0.f;
        __syncthreads();

        for (int task = tid; task < BT * NCSd; task += STPB) {
            int e = task / NCSd, i = task - e * NCSd;
            long b = (long)idxs[e];
            const float* srow = state + b * SW;
            float cap = srow[250 + 3 * i];
            int   bus = (int)srow[252 + 3 * i];
            float a   = action[b * NCSd + i];
            float conn = cap > 0.f ? 1.f : 0.f;
            float mch = fminf(22.0f,  conn * (70.0f - cap) * 4.0f);
            float mds = fmaxf(-22.0f, conn * (15.0f - cap) * 4.0f);
            float p = fmaxf(fminf(22.17f * a, mch), mds);
            atomicAdd(&ev[e][bus], p);
        }
        __syncthreads();

        float Sre[BT], Sim[BT], vr[BT], vi[BT];
        #pragma unroll
        for (int e = 0; e < BT; ++e) {
            long b = (long)idxs[e];
            float ap = jok ? state[b * SW + 4 + j]   : 0.f;
            float rp = jok ? state[b * SW + 127 + j] : 0.f;
            Sre[e] = (ap + ev[e][j]) * 0.001f;
            Sim[e] = rp * 0.001f;
            vr[e] = 1.f; vi[e] = 0.f;
        }
        for (int it = 0; it < 100; ++it) {
            #pragma unroll
            for (int e = 0; e < BT; ++e) {
                float d = vr[e] * vr[e] + vi[e] * vi[e];
                float inv = 1.0f / d;
                cmat[j][e] = make_float2((Sre[e] * vr[e] + Sim[e] * vi[e]) * inv,
                                         (Sre[e] * vi[e] - Sim[e] * vr[e]) * inv);
            }
            __syncthreads();
            float ar[BT], ai[BT];
            #pragma unroll
            for (int e = 0; e < BT; ++e) { ar[e] = Wre; ai[e] = Wim; }
            for (int k = 0; k < NB1; ++k) {
                float kr = jok ? Kre[j * NB1 + k] : 0.f;
                float ki = jok ? Kim[j * NB1 + k] : 0.f;
                const float4* crow = (const float4*)(&cmat[k][0]);
                #pragma unroll
                for (int eh = 0; eh < BT / 2; ++eh) {
                    float4 c2 = crow[eh];
                    ar[2*eh]   = fmaf(kr, c2.x, fmaf(-ki, c2.y, ar[2*eh]));
                    ai[2*eh]   = fmaf(kr, c2.y, fmaf( ki, c2.x, ai[2*eh]));
                    ar[2*eh+1] = fmaf(kr, c2.z, fmaf(-ki, c2.w, ar[2*eh+1]));
                    ai[2*eh+1] = fmaf(kr, c2.w, fmaf( ki, c2.z, ai[2*eh+1]));
                }
            }
            float md = 0.f;
            #pragma unroll
            for (int e = 0; e < BT; ++e) {
                float vmn = sqrtf(ar[e]*ar[e] + ai[e]*ai[e]);
                float vmo = sqrtf(vr[e]*vr[e] + vi[e]*vi[e]);
                md = fmaxf(md, fabsf(vmn - vmo));
                vr[e] = ar[e]; vi[e] = ai[e];
            }
            #pragma unroll
            for (int off = 32; off; off >>= 1) md = fmaxf(md, __shfl_xor(md, off));
            if ((tid & 63) == 0) red[tid >> 6] = md;
            __syncthreads();
            if (fmaxf(red[0], red[1]) < 1e-6f) break;
        }
        #pragma unroll
        for (int e = 0; e < BT; ++e) {
            float vm = sqrtf(vr[e]*vr[e] + vi[e]*vi[e]);
            vls[j][e] = jok ? fminf(0.f, 0.05f - fabsf(1.0f - vm)) : 0.f;
        }
        __syncthreads();
        if (tid < (int)nv) {
            float s = 0.f;
            for (int k = 0; k < NB1; ++k) s += vls[k][tid];
            long b = (long)idxs[tid];
            out[b] += 1000.0f * s;
        }
        __syncthreads();
    }
}

// ================= legacy full-solve path (used only if ws too small) =================
__global__ __launch_bounds__(STPB) void k_main(
    const float* __restrict__ action, const float* __restrict__ state,
    const float* __restrict__ Kre, const float* __restrict__ Kim,
    const float* __restrict__ Lre, const float* __restrict__ Lim,
    float* __restrict__ out)
{
    __shared__ float ev[BT][STPB];
    __shared__ float costs_s[BT];
    __shared__ float usat_s[BT];
    __shared__ __align__(16) float2 cmat[STPB][BT + 2];
    __shared__ float vls[STPB][BT + 1];
    __shared__ float red[2];
    const int tid = threadIdx.x;
    const int e0  = blockIdx.x * BT;
    for (int x = tid; x < BT * STPB; x += STPB) ((float*)ev)[x] = 0.f;
    if (tid < BT) { costs_s[tid] = 0.f; usat_s[tid] = 0.f; }
    __syncthreads();
    for (int task = tid; task < BT * NCSd; task += STPB) {
        int e = task / NCSd, i = task - e * NCSd;
        long b = (long)(e0 + e);
        const float* srow = state + b * SW;
        float cap = srow[250 + 3 * i], tleft = srow[251 + 3 * i];
        int bus = (int)srow[252 + 3 * i];
        float a = action[b * NCSd + i];
        float conn = cap > 0.f ? 1.f : 0.f;
        float mch = fminf(22.0f, conn * (70.0f - cap) * 4.0f);
        float mds = fmaxf(-22.0f, conn * (15.0f - cap) * 4.0f);
        float power = fmaxf(fminf(22.17f * a, mch), mds);
        atomicAdd(&costs_s[e], srow[3] * power * 0.25f);
        float nc = ceilf((cap + power * 0.25f) * 100.0f) * 0.01f;
        if (tleft == 1.0f) { float d = nc - 70.0f; atomicAdd(&usat_s[e], -10.0f * d * d); }
        atomicAdd(&ev[e][bus], power);
    }
    __syncthreads();
    const int j = tid;
    const bool jok = j < NB1;
    float Wre = jok ? Lre[j] : 1.0f, Wim = jok ? Lim[j] : 0.0f;
    float Sre[BT], Sim[BT], vr[BT], vi[BT];
    #pragma unroll
    for (int e = 0; e < BT; ++e) {
        long b = (long)(e0 + e);
        float ap = jok ? state[b * SW + 4 + j] : 0.f;
        float rp = jok ? state[b * SW + 127 + j] : 0.f;
        Sre[e] = (ap + ev[e][j]) * 0.001f; Sim[e] = rp * 0.001f;
        vr[e] = 1.f; vi[e] = 0.f;
    }
    for (int it = 0; it < 100; ++it) {
        #pragma unroll
        for (int e = 0; e < BT; ++e) {
            float d = vr[e]*vr[e] + vi[e]*vi[e];
            float inv = 1.0f / d;
            cmat[j][e] = make_float2((Sre[e]*vr[e] + Sim[e]*vi[e]) * inv,
                                     (Sre[e]*vi[e] - Sim[e]*vr[e]) * inv);
        }
        __syncthreads();
        float ar[BT], ai[BT];
        #pragma unroll
        for (int e = 0; e < BT; ++e) { ar[e] = Wre; ai[e] = Wim; }
        for (int k = 0; k < NB1; ++k) {
            float kr = jok ? Kre[j*NB1+k] : 0.f;
            float ki = jok ? Kim[j*NB1+k] : 0.f;
            const float4* crow = (const float4*)(&cmat[k][0]);
            #pragma unroll
            for (int eh = 0; eh < BT / 2; ++eh) {
                float4 c2 = crow[eh];
                ar[2*eh]   = fmaf(kr, c2.x, fmaf(-ki, c2.y, ar[2*eh]));
                ai[2*eh]   = fmaf(kr, c2.y, fmaf( ki, c2.x, ai[2*eh]));
                ar[2*eh+1] = fmaf(kr, c2.z, fmaf(-ki, c2.w, ar[2*eh+1]));
                ai[2*eh+1] = fmaf(kr, c2.w, fmaf( ki, c2.z, ai[2*eh+1]));
            }
        }
        float md = 0.f;
        #pragma unroll
        for (int e = 0; e < BT; ++e) {
            float vmn = sqrtf(ar[e]*ar[e] + ai[e]*ai[e]);
            float vmo = sqrtf(vr[e]*vr[e] + vi[e]*vi[e]);
            md = fmaxf(md, fabsf(vmn - vmo));
            vr[e] = ar[e]; vi[e] = ai[e];
        }
        #pragma unroll
        for (int off = 32; off > 0; off >>= 1) md = fmaxf(md, __shfl_xor(md, off));
        if ((tid & 63) == 0) red[tid >> 6] = md;
        __syncthreads();
        if (fmaxf(red[0], red[1]) < 1e-6f) break;
    }
    #pragma unroll
    for (int e = 0; e < BT; ++e) {
        float vm = sqrtf(vr[e]*vr[e] + vi[e]*vi[e]);
        vls[j][e] = jok ? fminf(0.f, 0.05f - fabsf(1.0f - vm)) : 0.f;
    }
    __syncthreads();
    if (tid < BT) {
        float s = 0.f;
        for (int k = 0; k < NB1; ++k) s += vls[k][tid];
        out[e0 + tid] = 1000.0f * s + costs_s[tid] + usat_s[tid];
    }
}

extern "C" void kernel_launch(void* const* d_in, const int* in_sizes, int n_in,
                              void* d_out, int out_size, void* d_ws, size_t ws_size,
                              hipStream_t stream) {
    const float* action = (const float*)d_in[0];
    const float* state  = (const float*)d_in[1];
    const float* Kre    = (const float*)d_in[2];
    const float* Kim    = (const float*)d_in[3];
    const float* Lre    = (const float*)d_in[4];
    const float* Lim    = (const float*)d_in[5];
    float* out = (float*)d_out;
    const int B = out_size;                        // 32768

    const size_t wsNeed = (size_t)(3 + B) * sizeof(unsigned);
    if (ws_size >= wsNeed) {
        float* ws = (float*)d_ws;
        hipLaunchKernelGGL(k_norm, dim3(1), dim3(512), 0, stream, Kre, Kim, Lre, Lim, ws);
        hipLaunchKernelGGL(k_fast, dim3(B / EPB), dim3(TPB), 0, stream,
                           action, state, ws, out);
        hipLaunchKernelGGL(k_solve, dim3(64), dim3(STPB), 0, stream,
                           action, state, Kre, Kim, Lre, Lim, ws, out);
    } else {
        hipLaunchKernelGGL(k_main, dim3((B + BT - 1) / BT), dim3(STPB), 0, stream,
                           action, state, Kre, Kim, Lre, Lim, out);
    }
}

// Round 6
// 45.380 us; speedup vs baseline: 1.5624x; 1.1161x over previous
//
#include <hip/hip_runtime.h>

#define NB1   123
#define NCSd  96
#define SW    538
#define SROW  540     // LDS row stride (floats), 2160B -> 16B aligned
#define EPB   8       // elements per block
#define TPB   256
#define BT    16      // legacy path
#define STPB  128

// ws: [0] float R = max_j ||K_j||_2 ; [1] float dW = max_j |W_j - 1|

// ---- R/dW: one block, 8 waves ----
__global__ __launch_bounds__(512) void k_norm(const float* __restrict__ Kre,
                                              const float* __restrict__ Kim,
                                              const float* __restrict__ Lre,
                                              const float* __restrict__ Lim,
                                              float* __restrict__ ws) {
    __shared__ float wred[16];
    const int tid = threadIdx.x;
    const int w = tid >> 6, l = tid & 63;
    float rmax2 = 0.f;
    for (int j = w; j < NB1; j += 8) {
        const float* kr = Kre + j * NB1;
        const float* ki = Kim + j * NB1;
        float a = kr[l], bb = ki[l];
        float s = fmaf(a, a, bb * bb);
        if (l + 64 < NB1) {
            float a2 = kr[l + 64], b2 = ki[l + 64];
            s = fmaf(a2, a2, fmaf(b2, b2, s));
        }
        #pragma unroll
        for (int off = 32; off; off >>= 1) s += __shfl_xor(s, off);
        rmax2 = fmaxf(rmax2, s);
    }
    float dw2 = 0.f;
    if (w == 0) {
        float dr = Lre[l] - 1.f, di = Lim[l];
        dw2 = fmaf(dr, dr, di * di);
        if (l + 64 < NB1) {
            float dr2 = Lre[l + 64] - 1.f, di2 = Lim[l + 64];
            dw2 = fmaxf(dw2, fmaf(dr2, dr2, di2 * di2));
        }
        #pragma unroll
        for (int off = 32; off; off >>= 1) dw2 = fmaxf(dw2, __shfl_xor(dw2, off));
    }
    if (l == 0) { wred[w] = rmax2; wred[8 + w] = dw2; }
    __syncthreads();
    if (tid == 0) {
        float r2 = wred[0];
        #pragma unroll
        for (int i = 1; i < 8; ++i) r2 = fmaxf(r2, wred[i]);
        ws[0] = sqrtf(r2);
        ws[1] = sqrtf(wred[8]);
    }
}

// ---- main: register-pipelined staging (12 loads in flight), certificate,
//      inline exact solve on the (expected-never) flagged path ----
__global__ __launch_bounds__(TPB) void k_fast(const float* __restrict__ action,
                                              const float* __restrict__ state,
                                              const float* __restrict__ Kre,
                                              const float* __restrict__ Kim,
                                              const float* __restrict__ Lre,
                                              const float* __restrict__ Lim,
                                              const float* __restrict__ ws,
                                              float* __restrict__ out) {
    __shared__ __align__(16) float st[EPB * SROW];   // 17280 B
    __shared__ float sa[EPB * NCSd];                 // 3072 B
    __shared__ float ev[EPB][128];                   // 4096 B
    __shared__ float cre_s[128], cim_s[128], vls_s[128];
    __shared__ unsigned char flag_s[EPB];

    const int tid = threadIdx.x;
    const long e0 = (long)blockIdx.x * EPB;
    const int w = tid >> 6, l64 = tid & 63;

    // ---- issue ALL independent loads first (10 state f2 + 2 action f2) ----
    const float2* G1 = (const float2*)(state + (e0 + w) * SW);
    const float2* G2 = (const float2*)(state + (e0 + w + 4) * SW);
    const float2* A2 = (const float2*)(action + e0 * NCSd);
    float2 r0 = G1[l64];
    float2 r1 = G1[l64 + 64];
    float2 r2 = G1[l64 + 128];
    float2 r3 = G1[l64 + 192];
    float2 r4 = make_float2(0.f, 0.f); if (l64 < 13) r4 = G1[l64 + 256];
    float2 s0 = G2[l64];
    float2 s1 = G2[l64 + 64];
    float2 s2 = G2[l64 + 128];
    float2 s3 = G2[l64 + 192];
    float2 s4 = make_float2(0.f, 0.f); if (l64 < 13) s4 = G2[l64 + 256];
    float2 a0 = A2[tid];
    float2 a1 = make_float2(0.f, 0.f); if (tid < 128) a1 = A2[tid + 256];

    // ev zero (LDS-only, overlaps with loads)
    #pragma unroll
    for (int k = 0; k < 4; ++k) ((float*)ev)[tid + 256 * k] = 0.f;

    // ---- LDS writes (compiler waits on vmcnt per dependence) ----
    {
        float2* L1 = (float2*)(st + w * SROW);
        float2* L2 = (float2*)(st + (w + 4) * SROW);
        L1[l64] = r0; L1[l64 + 64] = r1; L1[l64 + 128] = r2; L1[l64 + 192] = r3;
        if (l64 < 13) L1[l64 + 256] = r4;
        L2[l64] = s0; L2[l64 + 64] = s1; L2[l64 + 128] = s2; L2[l64 + 192] = s3;
        if (l64 < 13) L2[l64 + 256] = s4;
        float2* SA = (float2*)sa;
        SA[tid] = a0; if (tid < 128) SA[tid + 256] = a1;
    }
    __syncthreads();

    // ---- Phase A: 32 lanes / element ----
    const int e = tid >> 5, l = tid & 31;
    const long b = e0 + e;
    const float* srow = st + e * SROW;
    const float pr = srow[3];
    float costL = 0.f, usatL = 0.f;
    #pragma unroll
    for (int s = 0; s < NCSd / 32; ++s) {
        int i = l + 32 * s;
        float cap = srow[250 + 3 * i];               // stride-3: conflict-free
        float tl  = srow[251 + 3 * i];
        int   bus = (int)srow[252 + 3 * i];
        float a   = sa[e * NCSd + i];
        float conn = cap > 0.f ? 1.f : 0.f;
        float mch = fminf(22.0f,  conn * (70.0f - cap) * 4.0f);   // /DT, DT=0.25
        float mds = fmaxf(-22.0f, conn * (15.0f - cap) * 4.0f);
        float p = fmaxf(fminf(22.17f * a, mch), mds);             // MAX_CS = -MIN_CS
        costL = fmaf(pr * p, 0.25f, costL);
        float nc = ceilf((cap + p * 0.25f) * 100.0f) * 0.01f;
        if (tl == 1.0f) { float d = nc - 70.0f; usatL = fmaf(-10.0f * d, d, usatL); }
        atomicAdd(&ev[e][bus], p);
    }
    __syncthreads();

    // q^2 = sum_k (ap+ev)^2 + rp^2
    float s2sum = 0.f;
    #pragma unroll
    for (int s = 0; s < 4; ++s) {
        int k = l + 32 * s;
        if (k < NB1) {
            float apv = srow[4 + k] + ev[e][k];
            float rpv = srow[127 + k];
            s2sum = fmaf(apv, apv, fmaf(rpv, rpv, s2sum));
        }
    }
    #pragma unroll
    for (int off = 16; off; off >>= 1) {
        s2sum += __shfl_xor(s2sum, off);
        costL += __shfl_xor(costL, off);
        usatL += __shfl_xor(usatL, off);
    }

    if (l == 0) {
        float q  = sqrtf(s2sum) * 0.001f;            // ||S||_2
        float R  = ws[0];
        float dW = ws[1];
        float x  = R * q * 1.001f + 1e-7f;           // fp-safety inflation
        float om = 1.0f - dW;
        float disc = om * om - 4.0f * x;
        bool safe = false;
        if (disc > 0.f) {
            float m = 0.5f * (om + sqrtf(disc));      // lower bound on |v_j|, all iterates
            safe = (dW + x / m) < 0.0495f;            // => every |1-|v|| < 0.05 => term == 0
        }
        flag_s[e] = safe ? 0 : 1;
        out[b] = costL + usatL;                      // voltage term certified zero
    }
    __syncthreads();

    // ---- rare path: exact fp32 solve, block-uniform branch ----
    bool any = false;
    #pragma unroll
    for (int i = 0; i < EPB; ++i) any = any || (flag_s[i] != 0);
    if (any) {
        const int j = tid;
        const bool jok = j < NB1;
        for (int fe = 0; fe < EPB; ++fe) {
            if (!flag_s[fe]) continue;
            const float* frow = st + fe * SROW;
            float Sre = jok ? (frow[4 + j] + ev[fe][j]) * 0.001f : 0.f;
            float Sim = jok ? frow[127 + j] * 0.001f : 0.f;
            float Wre = jok ? Lre[j] : 1.f;
            float Wim = jok ? Lim[j] : 0.f;
            float vr = 1.f, vi = 0.f;
            for (int it = 0; it < 32; ++it) {        // fp32 fixpoint well before 32
                float d = vr * vr + vi * vi;
                float inv = 1.0f / d;
                if (tid < 128) {
                    cre_s[tid] = jok ? (Sre * vr + Sim * vi) * inv : 0.f;
                    cim_s[tid] = jok ? (Sre * vi - Sim * vr) * inv : 0.f;
                }
                __syncthreads();
                float ar = Wre, ai = Wim;
                if (jok) {
                    for (int k = 0; k < NB1; ++k) {
                        float kr = Kre[j * NB1 + k], ki = Kim[j * NB1 + k];
                        ar = fmaf(kr, cre_s[k], fmaf(-ki, cim_s[k], ar));
                        ai = fmaf(kr, cim_s[k], fmaf( ki, cre_s[k], ai));
                    }
                }
                vr = ar; vi = ai;
                __syncthreads();
            }
            if (tid < 128) {
                float vm = sqrtf(vr * vr + vi * vi);
                vls_s[tid] = jok ? fminf(0.f, 0.05f - fabsf(1.0f - vm)) : 0.f;
            }
            __syncthreads();
            if (tid == 0) {
                float s = 0.f;
                for (int k = 0; k < NB1; ++k) s += vls_s[k];
                out[e0 + fe] += 1000.0f * s;
            }
            __syncthreads();
        }
    }
}

// ================= legacy full-solve path (used only if ws too small) =================
__global__ __launch_bounds__(STPB) void k_main(
    const float* __restrict__ action, const float* __restrict__ state,
    const float* __restrict__ Kre, const float* __restrict__ Kim,
    const float* __restrict__ Lre, const float* __restrict__ Lim,
    float* __restrict__ out)
{
    __shared__ float ev[BT][STPB];
    __shared__ float costs_s[BT];
    __shared__ float usat_s[BT];
    __shared__ __align__(16) float2 cmat[STPB][BT + 2];
    __shared__ float vls[STPB][BT + 1];
    __shared__ float red[2];
    const int tid = threadIdx.x;
    const int e0  = blockIdx.x * BT;
    for (int x = tid; x < BT * STPB; x += STPB) ((float*)ev)[x] = 0.f;
    if (tid < BT) { costs_s[tid] = 0.f; usat_s[tid] = 0.f; }
    __syncthreads();
    for (int task = tid; task < BT * NCSd; task += STPB) {
        int e = task / NCSd, i = task - e * NCSd;
        long b = (long)(e0 + e);
        const float* srow = state + b * SW;
        float cap = srow[250 + 3 * i], tleft = srow[251 + 3 * i];
        int bus = (int)srow[252 + 3 * i];
        float a = action[b * NCSd + i];
        float conn = cap > 0.f ? 1.f : 0.f;
        float mch = fminf(22.0f, conn * (70.0f - cap) * 4.0f);
        float mds = fmaxf(-22.0f, conn * (15.0f - cap) * 4.0f);
        float power = fmaxf(fminf(22.17f * a, mch), mds);
        atomicAdd(&costs_s[e], srow[3] * power * 0.25f);
        float nc = ceilf((cap + power * 0.25f) * 100.0f) * 0.01f;
        if (tleft == 1.0f) { float d = nc - 70.0f; atomicAdd(&usat_s[e], -10.0f * d * d); }
        atomicAdd(&ev[e][bus], power);
    }
    __syncthreads();
    const int j = tid;
    const bool jok = j < NB1;
    float Wre = jok ? Lre[j] : 1.0f, Wim = jok ? Lim[j] : 0.0f;
    float Sre[BT], Sim[BT], vr[BT], vi[BT];
    #pragma unroll
    for (int e = 0; e < BT; ++e) {
        long b = (long)(e0 + e);
        float ap = jok ? state[b * SW + 4 + j] : 0.f;
        float rp = jok ? state[b * SW + 127 + j] : 0.f;
        Sre[e] = (ap + ev[e][j]) * 0.001f; Sim[e] = rp * 0.001f;
        vr[e] = 1.f; vi[e] = 0.f;
    }
    for (int it = 0; it < 100; ++it) {
        #pragma unroll
        for (int e = 0; e < BT; ++e) {
            float d = vr[e]*vr[e] + vi[e]*vi[e];
            float inv = 1.0f / d;
            cmat[j][e] = make_float2((Sre[e]*vr[e] + Sim[e]*vi[e]) * inv,
                                     (Sre[e]*vi[e] - Sim[e]*vr[e]) * inv);
        }
        __syncthreads();
        float ar[BT], ai[BT];
        #pragma unroll
        for (int e = 0; e < BT; ++e) { ar[e] = Wre; ai[e] = Wim; }
        for (int k = 0; k < NB1; ++k) {
            float kr = jok ? Kre[j*NB1+k] : 0.f;
            float ki = jok ? Kim[j*NB1+k] : 0.f;
            const float4* crow = (const float4*)(&cmat[k][0]);
            #pragma unroll
            for (int eh = 0; eh < BT / 2; ++eh) {
                float4 c2 = crow[eh];
                ar[2*eh]   = fmaf(kr, c2.x, fmaf(-ki, c2.y, ar[2*eh]));
                ai[2*eh]   = fmaf(kr, c2.y, fmaf( ki, c2.x, ai[2*eh]));
                ar[2*eh+1] = fmaf(kr, c2.z, fmaf(-ki, c2.w, ar[2*eh+1]));
                ai[2*eh+1] = fmaf(kr, c2.w, fmaf( ki, c2.z, ai[2*eh+1]));
            }
        }
        float md = 0.f;
        #pragma unroll
        for (int e = 0; e < BT; ++e) {
            float vmn = sqrtf(ar[e]*ar[e] + ai[e]*ai[e]);
            float vmo = sqrtf(vr[e]*vr[e] + vi[e]*vi[e]);
            md = fmaxf(md, fabsf(vmn - vmo));
            vr[e] = ar[e]; vi[e] = ai[e];
        }
        #pragma unroll
        for (int off = 32; off > 0; off >>= 1) md = fmaxf(md, __shfl_xor(md, off));
        if ((tid & 63) == 0) red[tid >> 6] = md;
        __syncthreads();
        if (fmaxf(red[0], red[1]) < 1e-6f) break;
    }
    #pragma unroll
    for (int e = 0; e < BT; ++e) {
        float vm = sqrtf(vr[e]*vr[e] + vi[e]*vi[e]);
        vls[j][e] = jok ? fminf(0.f, 0.05f - fabsf(1.0f - vm)) : 0.f;
    }
    __syncthreads();
    if (tid < BT) {
        float s = 0.f;
        for (int k = 0; k < NB1; ++k) s += vls[k][tid];
        out[e0 + tid] = 1000.0f * s + costs_s[tid] + usat_s[tid];
    }
}

extern "C" void kernel_launch(void* const* d_in, const int* in_sizes, int n_in,
                              void* d_out, int out_size, void* d_ws, size_t ws_size,
                              hipStream_t stream) {
    const float* action = (const float*)d_in[0];
    const float* state  = (const float*)d_in[1];
    const float* Kre    = (const float*)d_in[2];
    const float* Kim    = (const float*)d_in[3];
    const float* Lre    = (const float*)d_in[4];
    const float* Lim    = (const float*)d_in[5];
    float* out = (float*)d_out;
    const int B = out_size;                        // 32768

    if (ws_size >= 2 * sizeof(float)) {
        float* ws = (float*)d_ws;
        hipLaunchKernelGGL(k_norm, dim3(1), dim3(512), 0, stream, Kre, Kim, Lre, Lim, ws);
        hipLaunchKernelGGL(k_fast, dim3(B / EPB), dim3(TPB), 0, stream,
                           action, state, Kre, Kim, Lre, Lim, ws, out);
    } else {
        hipLaunchKernelGGL(k_main, dim3((B + BT - 1) / BT), dim3(STPB), 0, stream,
                           action, state, Kre, Kim, Lre, Lim, out);
    }
}